// Round 5
// baseline (777.200 us; speedup 1.0000x reference)
//
#include <hip/hip_runtime.h>
#include <math.h>

#define B_ 128
#define T_ 64
#define PH2 54     // staged input rows: input row y -> row y+2 (0..53)
#define PW2 64     // staged input row stride: input col x -> col x+2 (0..63)
#define EMB 750
#define MROW 819200  // 8192*100, one partial slab

// exact identity tanh(x) = 1 - 2/(e^{2x}+1); handles +-inf gracefully.
__device__ __forceinline__ float fast_tanh(float x) {
  float e = __expf(2.f * x);
  return 1.f - 2.f / (e + 1.f);
}

// exact 2-op LeakyReLU: for x<0, 0.01x > x; for x>=0, x >= 0.01x.
__device__ __forceinline__ float leaky(float x) {
  return fmaxf(x, 0.01f * x);
}

// ---------------- Kernel 1: register-fused conv1+conv2 (one image per WG) --
// Thread task = (conv2 row i, 3-col block jb). Loads a 5x9 sIn window into
// registers ONCE (unconditionally in-bounds via shift-by-2 staging), then for
// each channel: conv1 3x7 patch in registers -> leaky -> conv2 partial.
// No conv1 LDS round-trip; no barriers in main body.
__global__ __launch_bounds__(256) void conv_embed_k(
    const float* __restrict__ In, const float* __restrict__ w1,
    const float* __restrict__ b1, const float* __restrict__ w2,
    const float* __restrict__ b2, float* __restrict__ E)
{
  __shared__ __align__(16) float sIn[PH2 * PW2];   // 3456 f = 13.8 KB

  const int tid = threadIdx.x;
  const int g = blockIdx.x;               // g = b*T + t
  const int b = g >> 6;
  const int t = g & 63;
  const float* src = In + (size_t)g * 3000;

  // zero all (double halo) then fill interior at (y+2, x+2)
  float4 z4 = make_float4(0.f, 0.f, 0.f, 0.f);
  float4* sIn4 = (float4*)sIn;            // 3456/4 = 864
  for (int i = tid; i < 864; i += 256) sIn4[i] = z4;
  __syncthreads();
  for (int i = tid; i < 3000; i += 256) {
    int y = i / 60, x = i - y * 60;
    sIn[(y + 2) * PW2 + (x + 2)] = src[i];
  }
  __syncthreads();

  if (tid < 250) {
    const int i  = tid / 10;          // conv2 row 0..24
    const int jb = tid - i * 10;      // col-block 0..9 (j = 3jb..3jb+2)
    const int j0 = 3 * jb;

    // 5x9 staged-input window; win[wr][wc] = sIn2[2i+wr][2j0+wc].
    // conv1(r,c) (r=2i-1+dy, c=2j0-1+m) = sum w[ky][kx]*win[dy+ky][m+kx].
    // All indices in-bounds: rows 2i..2i+4 <= 52, cols 2j0..2j0+8 <= 62.
    float win[5][9];
    {
      const float* wb0 = &sIn[(2 * i) * PW2 + 2 * j0];
      #pragma unroll
      for (int wr = 0; wr < 5; ++wr) {
        const float* rp = wb0 + wr * PW2;
        #pragma unroll
        for (int wc = 0; wc < 9; ++wc) win[wr][wc] = rp[wc];
      }
    }

    const float rm0 = (i == 0) ? 0.f : 1.f;    // conv1 row -1 is conv2 zero-pad
    const float cm0 = (jb == 0) ? 0.f : 1.f;   // conv1 col -1 is conv2 zero-pad
    float acc2[3] = {0.f, 0.f, 0.f};

    for (int cg = 0; cg < 4; ++cg) {
      #pragma unroll
      for (int cc = 0; cc < 4; ++cc) {
        const int ch = cg * 4 + cc;
        float wv[9], w2v[9];
        #pragma unroll
        for (int q = 0; q < 9; ++q) { wv[q] = w1[ch * 9 + q]; w2v[q] = w2[ch * 9 + q]; }
        const float bias = b1[ch];

        // conv1 3x7 patch: c1v[dy][m] = conv1 at (row 2i-1+dy, col 2j0-1+m)
        float c1v[3][7];
        #pragma unroll
        for (int dy = 0; dy < 3; ++dy) {
          #pragma unroll
          for (int m = 0; m < 7; ++m) {
            float a = bias;
            #pragma unroll
            for (int ky = 0; ky < 3; ++ky) {
              a += wv[ky * 3 + 0] * win[dy + ky][m + 0]
                 + wv[ky * 3 + 1] * win[dy + ky][m + 1]
                 + wv[ky * 3 + 2] * win[dy + ky][m + 2];
            }
            c1v[dy][m] = leaky(a);
          }
        }
        // conv2 zero-padding of conv1 output (row -1 / col -1)
        #pragma unroll
        for (int m = 0; m < 7; ++m) c1v[0][m] *= rm0;
        #pragma unroll
        for (int dy = 0; dy < 3; ++dy) c1v[dy][0] *= cm0;

        // conv2 (stride 2): output j = j0+jl reads c1v cols 2jl..2jl+2
        #pragma unroll
        for (int jl = 0; jl < 3; ++jl) {
          float s = acc2[jl];
          #pragma unroll
          for (int dy = 0; dy < 3; ++dy) {
            s += w2v[dy * 3 + 0] * c1v[dy][2 * jl + 0]
               + w2v[dy * 3 + 1] * c1v[dy][2 * jl + 1]
               + w2v[dy * 3 + 2] * c1v[dy][2 * jl + 2];
          }
          acc2[jl] = s;
        }
      }
    }

    const float b2v = b2[0];
    float* erow = E + (size_t)(t * B_ + b) * EMB + i * 30 + j0;
    #pragma unroll
    for (int jl = 0; jl < 3; ++jl) erow[jl] = leaky(acc2[jl] + b2v);
  }
}

// ------- Kernel 2/4: partial GEMM  Part[s] = A[M,Ka] @ W[Ka,100] (K-split) --
// grid = (64 M-tiles of 128 rows, NS=4 K-splits). 256 thr: 16 rgrp x 13 cgrp
// active (8x8 register tile, float4 LDS reads both operands, As transposed).
__global__ __launch_bounds__(256) void gemm_part_k(
    const float* __restrict__ A, const float* __restrict__ W,
    float* __restrict__ Part, int Ka, int tps)
{
  __shared__ __align__(16) float AsT[50 * 132];   // [kk][row0..127 +4 pad]
  __shared__ __align__(16) float Ws[50 * 104];    // [kk][col0..99 +4 pad]

  const int tid = threadIdx.x;
  const int m0 = blockIdx.x * 128;
  const int s  = blockIdx.y;
  const int ktotal = Ka / 50;
  const int kt0 = s * tps;
  const int nt  = min(tps, ktotal - kt0);
  float* part = Part + (size_t)s * MROW;

  const int rq = tid & 15;          // row group: rows rq*8 .. rq*8+7
  const int cq = tid >> 4;          // col group 0..15; active < 13
  const bool active = (cq < 13);
  const int lr0 = rq * 8;
  const int c0 = cq * 8;

  float acc[8][8];
  #pragma unroll
  for (int r = 0; r < 8; ++r)
    #pragma unroll
    for (int c = 0; c < 8; ++c) acc[r][c] = 0.f;

  for (int kt = 0; kt < nt; ++kt) {
    const int k0 = (kt0 + kt) * 50;
    for (int i = tid; i < 6400; i += 256) {       // 128 rows x 50 k
      int r = i / 50, kk = i - r * 50;
      AsT[kk * 132 + r] = A[(size_t)(m0 + r) * Ka + k0 + kk];
    }
    for (int i = tid; i < 5000; i += 256) {       // 50 k x 100 cols
      int kk = i / 100, c = i - kk * 100;
      Ws[kk * 104 + c] = W[(size_t)(k0 + kk) * 100 + c];
    }
    __syncthreads();
    if (active) {
      for (int kk = 0; kk < 50; ++kk) {
        float4 a0 = *(const float4*)&AsT[kk * 132 + lr0];
        float4 a1 = *(const float4*)&AsT[kk * 132 + lr0 + 4];
        float4 w0 = *(const float4*)&Ws[kk * 104 + c0];
        float4 w1v = *(const float4*)&Ws[kk * 104 + c0 + 4];
        float av[8] = {a0.x, a0.y, a0.z, a0.w, a1.x, a1.y, a1.z, a1.w};
        float wv[8] = {w0.x, w0.y, w0.z, w0.w, w1v.x, w1v.y, w1v.z, w1v.w};
        #pragma unroll
        for (int r = 0; r < 8; ++r)
          #pragma unroll
          for (int c = 0; c < 8; ++c) acc[r][c] += av[r] * wv[c];
      }
    }
    __syncthreads();
  }

  if (active) {
    #pragma unroll
    for (int r = 0; r < 8; ++r) {
      float* pp = part + (size_t)(m0 + lr0 + r) * 100 + c0;
      *(float4*)pp = make_float4(acc[r][0], acc[r][1], acc[r][2], acc[r][3]);
      if (cq < 12)   // col group 12 covers exactly cols 96..99
        *(float4*)(pp + 4) = make_float4(acc[r][4], acc[r][5], acc[r][6], acc[r][7]);
    }
  }
}

// ---------------- Kernel 3: sequential scan + fused H-scan ---------------
// One WG per batch sample. State G_a = H_a @ R_wa (linear in H).
// Staging folds the 4 EQ partials + Qb. R_w column-slices + Q_wB
// quarter-columns live in registers for all 64 steps.
__global__ __launch_bounds__(512) void scan_k(
    const float* __restrict__ EQp, const float* __restrict__ Qb,
    const float* __restrict__ Qw, const float* __restrict__ Rw,
    const float* __restrict__ Rb, float* __restrict__ Hf)
{
  __shared__ __align__(16) float sEQ[T_ * 100];   // 25.6 KB
  __shared__ __align__(16) float sQ[100];
  __shared__ float sR[100];
  __shared__ float sGred[400];
  __shared__ float sP2[400];

  const int tid = threadIdx.x;
  const int b = blockIdx.x;
  const bool owner = (tid < 400);
  const int a = tid / 100;            // 0..3 (also k-quarter in phase2)
  const int j = tid - a * 100;
  const float al = (a == 0) ? 0.f : (a == 1) ? 0.25f : (a == 2) ? 0.5f : 0.95f;

  // stage EQ column for this b: sum 4 partials + Qb (float4)
  {
    const float4* Qb4 = (const float4*)Qb;
    float4* sEQ4 = (float4*)sEQ;
    for (int i4 = tid; i4 < 1600; i4 += 512) {
      int tt = i4 / 25, j4 = i4 - tt * 25;
      size_t idx4 = (size_t)(tt * B_ + b) * 25 + j4;
      const float4* p0 = (const float4*)EQp;
      float4 v0 = p0[idx4];
      float4 v1 = p0[MROW / 4 + idx4];
      float4 v2 = p0[2 * (MROW / 4) + idx4];
      float4 v3 = p0[3 * (MROW / 4) + idx4];
      float4 qb = Qb4[j4];
      sEQ4[i4] = make_float4(v0.x + v1.x + v2.x + v3.x + qb.x,
                             v0.y + v1.y + v2.y + v3.y + qb.y,
                             v0.z + v1.z + v2.z + v3.z + qb.z,
                             v0.w + v1.w + v2.w + v3.w + qb.w);
    }
  }

  float rw[100];   // Rw[(a*100+k)*100 + j]
  float qw[25];    // Qw[(750 + a*25 + kk)*100 + j]
  if (owner) {
    const float* rp = Rw + (size_t)a * 10000 + j;
    #pragma unroll
    for (int k = 0; k < 100; ++k) rw[k] = rp[(size_t)k * 100];
    const float* qp = Qw + (size_t)(750 + a * 25) * 100 + j;
    #pragma unroll
    for (int kk = 0; kk < 25; ++kk) qw[kk] = qp[(size_t)kk * 100];
    sGred[tid] = 0.f;
  }
  const float rb = (tid < 100) ? Rb[tid] : 0.f;
  float g = 0.f;
  float h1 = 0.f, h2 = 0.f, h3 = 0.f;
  __syncthreads();

  for (int t = 0; t < T_; ++t) {
    // phase1: Rt = tanh(sum_a G_a + Rb)
    if (tid < 100) {
      float s = sGred[tid] + sGred[100 + tid] + sGred[200 + tid] + sGred[300 + tid] + rb;
      sR[tid] = fast_tanh(s);
    }
    __syncthreads();
    // phase2a: quarter-k partials of Rt @ QwB
    if (owner) {
      float p = 0.f;
      #pragma unroll
      for (int kk = 0; kk < 25; ++kk) p += sR[a * 25 + kk] * qw[kk];
      sP2[tid] = p;
    }
    __syncthreads();
    // phase2b: Qt = tanh(EQ + partials); fused H-scan + Hf writes
    if (tid < 100) {
      float q = fast_tanh(sEQ[t * 100 + tid] +
                          sP2[tid] + sP2[100 + tid] + sP2[200 + tid] + sP2[300 + tid]);
      sQ[tid] = q;
      h1 = 0.25f * h1 + 0.75f * q;
      h2 = 0.50f * h2 + 0.50f * q;
      h3 = 0.95f * h3 + 0.05f * q;
      float* hp = Hf + (size_t)(t * B_ + b) * 400 + tid;
      hp[0] = q; hp[100] = h1; hp[200] = h2; hp[300] = h3;
    }
    __syncthreads();
    // phase3: G_a = al*G_a + (1-al) * (Qt @ R_wa)
    if (owner) {
      float d = 0.f;
      const float4* q4 = (const float4*)sQ;
      #pragma unroll
      for (int k4 = 0; k4 < 25; ++k4) {
        float4 qv = q4[k4];
        d += qv.x * rw[k4 * 4] + qv.y * rw[k4 * 4 + 1]
           + qv.z * rw[k4 * 4 + 2] + qv.w * rw[k4 * 4 + 3];
      }
      g = al * g + (1.f - al) * d;
      sGred[tid] = g;
    }
    __syncthreads();
  }
}

// ------- Kernel 5: fold O partials -> tanh -> classifier + softmax ---------
__global__ __launch_bounds__(256) void final_k(
    const float* __restrict__ Opart, const float* __restrict__ Ob,
    const float* __restrict__ OutW, const float* __restrict__ OutB,
    float* __restrict__ out)
{
  __shared__ float wred[4][10];
  __shared__ float lg[10];
  const int tid = threadIdx.x;
  const int b = blockIdx.x;
  float acc[10];
  #pragma unroll
  for (int c = 0; c < 10; ++c) acc[c] = 0.f;

  for (int k = tid; k < 6400; k += 256) {
    int t = k / 100, j = k - t * 100;
    size_t idx = (size_t)(t * B_ + b) * 100 + j;
    float p = Opart[idx] + Opart[MROW + idx] + Opart[2 * MROW + idx] + Opart[3 * MROW + idx];
    float o = fast_tanh(p + Ob[j]);
    const float* w = OutW + (size_t)k * 10;
    #pragma unroll
    for (int c = 0; c < 10; ++c) acc[c] += o * w[c];
  }
  // wave tree-reduce then cross-wave
  #pragma unroll
  for (int sdl = 32; sdl >= 1; sdl >>= 1) {
    #pragma unroll
    for (int c = 0; c < 10; ++c) acc[c] += __shfl_down(acc[c], sdl, 64);
  }
  const int wid = tid >> 6, lane = tid & 63;
  if (lane == 0) {
    #pragma unroll
    for (int c = 0; c < 10; ++c) wred[wid][c] = acc[c];
  }
  __syncthreads();
  if (tid < 10) {
    lg[tid] = OutB[tid] + wred[0][tid] + wred[1][tid] + wred[2][tid] + wred[3][tid];
  }
  __syncthreads();
  if (tid == 0) {
    float mx = lg[0];
    #pragma unroll
    for (int c = 1; c < 10; ++c) mx = fmaxf(mx, lg[c]);
    float e[10], ssum = 0.f;
    #pragma unroll
    for (int c = 0; c < 10; ++c) { e[c] = expf(lg[c] - mx); ssum += e[c]; }
    float inv = 1.f / ssum;
    #pragma unroll
    for (int c = 0; c < 10; ++c) out[b * 10 + c] = e[c] * inv;
  }
}

extern "C" void kernel_launch(void* const* d_in, const int* in_sizes, int n_in,
                              void* d_out, int out_size, void* d_ws, size_t ws_size,
                              hipStream_t stream)
{
  const float* In   = (const float*)d_in[0];
  const float* w1   = (const float*)d_in[1];
  const float* b1   = (const float*)d_in[2];
  const float* w2   = (const float*)d_in[3];
  const float* b2   = (const float*)d_in[4];
  const float* Rw   = (const float*)d_in[5];
  const float* Rb   = (const float*)d_in[6];
  const float* Qw   = (const float*)d_in[7];
  const float* Qb   = (const float*)d_in[8];
  const float* Ow   = (const float*)d_in[9];
  const float* Ob   = (const float*)d_in[10];
  const float* OutW = (const float*)d_in[11];
  const float* OutB = (const float*)d_in[12];
  float* out = (float*)d_out;

  float* ws  = (float*)d_ws;
  float* E   = ws;                   // [8192][750] = 24.58 MB   rows t*B+b
  float* EQp = E + 6144000;          // [4][8192][100] = 13.1 MB (EQ partials)
  float* Hf  = EQp + 4 * MROW;       // [8192][400] = 13.1 MB
  float* Op  = EQp;                  // O partials alias EQp (dead after scan)
  // total ~50.8 MB of d_ws

  hipLaunchKernelGGL(conv_embed_k, dim3(B_ * T_), dim3(256), 0, stream,
                     In, w1, b1, w2, b2, E);
  hipLaunchKernelGGL(gemm_part_k, dim3(64, 4), dim3(256), 0, stream,
                     E, Qw, EQp, 750, 4);
  hipLaunchKernelGGL(scan_k, dim3(B_), dim3(512), 0, stream,
                     EQp, Qb, Qw, Rw, Rb, Hf);
  hipLaunchKernelGGL(gemm_part_k, dim3(64, 4), dim3(256), 0, stream,
                     Hf, Ow, Op, 400, 2);
  hipLaunchKernelGGL(final_k, dim3(B_), dim3(256), 0, stream,
                     Op, Ob, OutW, OutB, out);
}

// Round 7
// 653.752 us; speedup vs baseline: 1.1888x; 1.1888x over previous
//
#include <hip/hip_runtime.h>
#include <math.h>

#define B_ 128
#define T_ 64
#define PH2 54     // staged input rows: input row y -> row y+2 (0..53)
#define PW2 64     // staged input row stride: input col x -> col x+2 (0..63)
#define EMB 750
#define MROW 819200  // 8192*100, one partial slab

// exact identity tanh(x) = 1 - 2/(e^{2x}+1); handles +-inf gracefully.
__device__ __forceinline__ float fast_tanh(float x) {
  float e = __expf(2.f * x);
  return 1.f - 2.f / (e + 1.f);
}

// exact 2-op LeakyReLU: for x<0, 0.01x > x; for x>=0, x >= 0.01x.
__device__ __forceinline__ float leaky(float x) {
  return fmaxf(x, 0.01f * x);
}

// ---------------- Kernel 1: output-stationary scatter conv (1 img/WG) -----
// Each thread owns one conv1 pixel: 9 LDS reads, 16 channels computed ONCE
// (work-optimal 432K FMA/image), each channel folded immediately into the
// <=4 conv2 outputs it touches (atomicAdd into 750-float LDS accumulator).
// Pixel ids quadrant-remapped so (r&1,c&1) is wave-uniform (no divergence).
__global__ __launch_bounds__(256) void conv_embed_k(
    const float* __restrict__ In, const float* __restrict__ w1,
    const float* __restrict__ b1, const float* __restrict__ w2,
    const float* __restrict__ b2, float* __restrict__ E)
{
  __shared__ __align__(16) float sIn[PH2 * PW2];   // 3456 f = 13.8 KB
  __shared__ __align__(16) float sAcc[768];        // conv2 acc [i*30+j], 750 used

  const int tid = threadIdx.x;
  const int g = blockIdx.x;               // g = b*T + t
  const int b = g >> 6;
  const int t = g & 63;
  const float* src = In + (size_t)g * 3000;

  // zero both buffers, then fill interior at (y+2, x+2)
  float4 z4 = make_float4(0.f, 0.f, 0.f, 0.f);
  float4* sIn4 = (float4*)sIn;            // 864 quads
  for (int i = tid; i < 864; i += 256) sIn4[i] = z4;
  float4* sAcc4 = (float4*)sAcc;          // 192 quads
  for (int i = tid; i < 192; i += 256) sAcc4[i] = z4;
  __syncthreads();
  for (int i = tid; i < 3000; i += 256) {
    int y = i / 60, x = i - y * 60;
    sIn[(y + 2) * PW2 + (x + 2)] = src[i];
  }
  __syncthreads();

  // conv1 for one pixel (all-in-registers window), leaky'd
  for (int it = 0; it < 12; ++it) {
    const int id = tid + it * 256;
    if (id < 3000) {
      // quadrant-major remap: quad = (r&1)*2 + (c&1), wave-uniform
      const int quad  = id / 750;
      const int rem   = id - quad * 750;
      const int rhalf = rem / 30;          // 0..24
      const int cc2   = rem - rhalf * 30;  // 0..29
      const int rp = quad >> 1, cp = quad & 1;
      const int r = 2 * rhalf + rp;        // 0..49
      const int c = 2 * cc2 + cp;          // 0..59

      // 3x3 input window: input (r-1+ky, c-1+kx) -> staged (r+1+ky, c+1+kx)
      float win[3][3];
      {
        const float* wb = &sIn[(r + 1) * PW2 + (c + 1)];
        #pragma unroll
        for (int ky = 0; ky < 3; ++ky) {
          #pragma unroll
          for (int kx = 0; kx < 3; ++kx) win[ky][kx] = wb[ky * PW2 + kx];
        }
      }

      // per-channel conv1 value (leaky'd)
      auto c1v = [&](int ch) -> float {
        float a = b1[ch];
        #pragma unroll
        for (int ky = 0; ky < 3; ++ky) {
          a += w1[ch * 9 + ky * 3 + 0] * win[ky][0]
             + w1[ch * 9 + ky * 3 + 1] * win[ky][1]
             + w1[ch * 9 + ky * 3 + 2] * win[ky][2];
        }
        return leaky(a);
      };

      // conv2 targets: rows: rp==0 -> (rhalf, dy=1); rp==1 -> (rhalf, dy=2)
      // and (rhalf+1, dy=0) if rhalf<24. cols symmetric with cc2/cp, dx.
      float s00 = 0.f, s01 = 0.f, s10 = 0.f, s11 = 0.f;
      if (quad == 0) {
        #pragma unroll
        for (int ch = 0; ch < 16; ++ch) { float a = c1v(ch); s00 += a * w2[ch * 9 + 4]; }
      } else if (quad == 1) {
        #pragma unroll
        for (int ch = 0; ch < 16; ++ch) {
          float a = c1v(ch);
          s00 += a * w2[ch * 9 + 5]; s01 += a * w2[ch * 9 + 3];
        }
      } else if (quad == 2) {
        #pragma unroll
        for (int ch = 0; ch < 16; ++ch) {
          float a = c1v(ch);
          s00 += a * w2[ch * 9 + 7]; s10 += a * w2[ch * 9 + 1];
        }
      } else {
        #pragma unroll
        for (int ch = 0; ch < 16; ++ch) {
          float a = c1v(ch);
          s00 += a * w2[ch * 9 + 8]; s01 += a * w2[ch * 9 + 6];
          s10 += a * w2[ch * 9 + 2]; s11 += a * w2[ch * 9 + 0];
        }
      }

      const int base = rhalf * 30 + cc2;
      atomicAdd(&sAcc[base], s00);
      if (cp && cc2 < 29)               atomicAdd(&sAcc[base + 1], s01);
      if (rp && rhalf < 24)             atomicAdd(&sAcc[base + 30], s10);
      if (rp && cp && rhalf < 24 && cc2 < 29) atomicAdd(&sAcc[base + 31], s11);
    }
  }
  __syncthreads();

  const float b2v = b2[0];
  float* erow = E + (size_t)(t * B_ + b) * EMB;
  for (int p = tid; p < 750; p += 256) erow[p] = leaky(sAcc[p] + b2v);
}

// ------- Kernel 2/4: partial GEMM  Part[s] = A[M,Ka] @ W[Ka,100] (K-split) --
__global__ __launch_bounds__(256) void gemm_part_k(
    const float* __restrict__ A, const float* __restrict__ W,
    float* __restrict__ Part, int Ka, int tps)
{
  __shared__ __align__(16) float AsT[50 * 132];   // [kk][row0..127 +4 pad]
  __shared__ __align__(16) float Ws[50 * 104];    // [kk][col0..99 +4 pad]

  const int tid = threadIdx.x;
  const int m0 = blockIdx.x * 128;
  const int s  = blockIdx.y;
  const int ktotal = Ka / 50;
  const int kt0 = s * tps;
  const int nt  = min(tps, ktotal - kt0);
  float* part = Part + (size_t)s * MROW;

  const int rq = tid & 15;
  const int cq = tid >> 4;
  const bool active = (cq < 13);
  const int lr0 = rq * 8;
  const int c0 = cq * 8;

  float acc[8][8];
  #pragma unroll
  for (int r = 0; r < 8; ++r)
    #pragma unroll
    for (int c = 0; c < 8; ++c) acc[r][c] = 0.f;

  for (int kt = 0; kt < nt; ++kt) {
    const int k0 = (kt0 + kt) * 50;
    for (int i = tid; i < 6400; i += 256) {
      int r = i / 50, kk = i - r * 50;
      AsT[kk * 132 + r] = A[(size_t)(m0 + r) * Ka + k0 + kk];
    }
    for (int i = tid; i < 5000; i += 256) {
      int kk = i / 100, c = i - kk * 100;
      Ws[kk * 104 + c] = W[(size_t)(k0 + kk) * 100 + c];
    }
    __syncthreads();
    if (active) {
      for (int kk = 0; kk < 50; ++kk) {
        float4 a0 = *(const float4*)&AsT[kk * 132 + lr0];
        float4 a1 = *(const float4*)&AsT[kk * 132 + lr0 + 4];
        float4 w0 = *(const float4*)&Ws[kk * 104 + c0];
        float4 w1v = *(const float4*)&Ws[kk * 104 + c0 + 4];
        float av[8] = {a0.x, a0.y, a0.z, a0.w, a1.x, a1.y, a1.z, a1.w};
        float wv[8] = {w0.x, w0.y, w0.z, w0.w, w1v.x, w1v.y, w1v.z, w1v.w};
        #pragma unroll
        for (int r = 0; r < 8; ++r)
          #pragma unroll
          for (int c = 0; c < 8; ++c) acc[r][c] += av[r] * wv[c];
      }
    }
    __syncthreads();
  }

  if (active) {
    #pragma unroll
    for (int r = 0; r < 8; ++r) {
      float* pp = part + (size_t)(m0 + lr0 + r) * 100 + c0;
      *(float4*)pp = make_float4(acc[r][0], acc[r][1], acc[r][2], acc[r][3]);
      if (cq < 12)
        *(float4*)(pp + 4) = make_float4(acc[r][4], acc[r][5], acc[r][6], acc[r][7]);
    }
  }
}

// ---------------- Kernel 3: sequential scan + fused H-scan (validated) ----
__global__ __launch_bounds__(512) void scan_k(
    const float* __restrict__ EQp, const float* __restrict__ Qb,
    const float* __restrict__ Qw, const float* __restrict__ Rw,
    const float* __restrict__ Rb, float* __restrict__ Hf)
{
  __shared__ __align__(16) float sEQ[T_ * 100];   // 25.6 KB
  __shared__ __align__(16) float sQ[100];
  __shared__ float sR[100];
  __shared__ float sGred[400];
  __shared__ float sP2[400];

  const int tid = threadIdx.x;
  const int b = blockIdx.x;
  const bool owner = (tid < 400);
  const int a = tid / 100;
  const int j = tid - a * 100;
  const float al = (a == 0) ? 0.f : (a == 1) ? 0.25f : (a == 2) ? 0.5f : 0.95f;

  {
    const float4* Qb4 = (const float4*)Qb;
    float4* sEQ4 = (float4*)sEQ;
    for (int i4 = tid; i4 < 1600; i4 += 512) {
      int tt = i4 / 25, j4 = i4 - tt * 25;
      size_t idx4 = (size_t)(tt * B_ + b) * 25 + j4;
      const float4* p0 = (const float4*)EQp;
      float4 v0 = p0[idx4];
      float4 v1 = p0[MROW / 4 + idx4];
      float4 v2 = p0[2 * (MROW / 4) + idx4];
      float4 v3 = p0[3 * (MROW / 4) + idx4];
      float4 qb = Qb4[j4];
      sEQ4[i4] = make_float4(v0.x + v1.x + v2.x + v3.x + qb.x,
                             v0.y + v1.y + v2.y + v3.y + qb.y,
                             v0.z + v1.z + v2.z + v3.z + qb.z,
                             v0.w + v1.w + v2.w + v3.w + qb.w);
    }
  }

  float rw[100];
  float qw[25];
  if (owner) {
    const float* rp = Rw + (size_t)a * 10000 + j;
    #pragma unroll
    for (int k = 0; k < 100; ++k) rw[k] = rp[(size_t)k * 100];
    const float* qp = Qw + (size_t)(750 + a * 25) * 100 + j;
    #pragma unroll
    for (int kk = 0; kk < 25; ++kk) qw[kk] = qp[(size_t)kk * 100];
    sGred[tid] = 0.f;
  }
  const float rb = (tid < 100) ? Rb[tid] : 0.f;
  float g = 0.f;
  float h1 = 0.f, h2 = 0.f, h3 = 0.f;
  __syncthreads();

  for (int t = 0; t < T_; ++t) {
    if (tid < 100) {
      float s = sGred[tid] + sGred[100 + tid] + sGred[200 + tid] + sGred[300 + tid] + rb;
      sR[tid] = fast_tanh(s);
    }
    __syncthreads();
    if (owner) {
      float p = 0.f;
      #pragma unroll
      for (int kk = 0; kk < 25; ++kk) p += sR[a * 25 + kk] * qw[kk];
      sP2[tid] = p;
    }
    __syncthreads();
    if (tid < 100) {
      float q = fast_tanh(sEQ[t * 100 + tid] +
                          sP2[tid] + sP2[100 + tid] + sP2[200 + tid] + sP2[300 + tid]);
      sQ[tid] = q;
      h1 = 0.25f * h1 + 0.75f * q;
      h2 = 0.50f * h2 + 0.50f * q;
      h3 = 0.95f * h3 + 0.05f * q;
      float* hp = Hf + (size_t)(t * B_ + b) * 400 + tid;
      hp[0] = q; hp[100] = h1; hp[200] = h2; hp[300] = h3;
    }
    __syncthreads();
    if (owner) {
      float d = 0.f;
      const float4* q4 = (const float4*)sQ;
      #pragma unroll
      for (int k4 = 0; k4 < 25; ++k4) {
        float4 qv = q4[k4];
        d += qv.x * rw[k4 * 4] + qv.y * rw[k4 * 4 + 1]
           + qv.z * rw[k4 * 4 + 2] + qv.w * rw[k4 * 4 + 3];
      }
      g = al * g + (1.f - al) * d;
      sGred[tid] = g;
    }
    __syncthreads();
  }
}

// ------- Kernel 5: split-K logits partials. Block kb owns k in [kb*100, +100).
// OutW is read exactly ONCE across the grid (vs 128x before). Deterministic.
__global__ __launch_bounds__(256) void out_gemm_k(
    const float* __restrict__ Opart, const float* __restrict__ Ob,
    const float* __restrict__ OutW, float* __restrict__ Pl)
{
  __shared__ float sW[1000];           // OutW rows kb*100 .. +99 (x10 cols)
  __shared__ float sOb[100];
  const int tid = threadIdx.x;
  const int kb = blockIdx.x;           // 0..63 == t
  for (int i = tid; i < 1000; i += 256) sW[i] = OutW[kb * 1000 + i];
  if (tid < 100) sOb[tid] = Ob[tid];
  __syncthreads();

  const int bb = tid >> 1;             // sample 0..127
  const int half = tid & 1;            // k-half
  const size_t row = (size_t)kb * B_ + bb;   // Opart row t*B+b
  float acc[10];
  #pragma unroll
  for (int c = 0; c < 10; ++c) acc[c] = 0.f;

  for (int kk = 0; kk < 50; ++kk) {
    const int off = half * 50 + kk;    // j = k % 100
    const size_t idx = row * 100 + off;
    float p = Opart[idx] + Opart[MROW + idx] + Opart[2 * MROW + idx] + Opart[3 * MROW + idx];
    float o = fast_tanh(p + sOb[off]);
    const float* w = &sW[off * 10];
    #pragma unroll
    for (int c = 0; c < 10; ++c) acc[c] += o * w[c];
  }
  #pragma unroll
  for (int c = 0; c < 10; ++c) acc[c] += __shfl_xor(acc[c], 1, 2);
  if (half == 0) {
    float* pp = &Pl[(size_t)kb * 1280 + bb * 10];
    #pragma unroll
    for (int c = 0; c < 10; ++c) pp[c] = acc[c];
  }
}

// ------- Kernel 6: reduce 64 partials + bias + softmax. 128 blocks x 64 thr.
__global__ __launch_bounds__(64) void softmax_k(
    const float* __restrict__ Pl, const float* __restrict__ OutB,
    float* __restrict__ out)
{
  const int b = blockIdx.x;
  const int lane = threadIdx.x;        // = kb
  float acc[10];
  const float* pp = &Pl[(size_t)lane * 1280 + b * 10];
  #pragma unroll
  for (int c = 0; c < 10; ++c) acc[c] = pp[c];
  #pragma unroll
  for (int sdl = 32; sdl >= 1; sdl >>= 1) {
    #pragma unroll
    for (int c = 0; c < 10; ++c) acc[c] += __shfl_down(acc[c], sdl, 64);
  }
  if (lane == 0) {
    float lg[10];
    #pragma unroll
    for (int c = 0; c < 10; ++c) lg[c] = acc[c] + OutB[c];
    float mx = lg[0];
    #pragma unroll
    for (int c = 1; c < 10; ++c) mx = fmaxf(mx, lg[c]);
    float e[10], ssum = 0.f;
    #pragma unroll
    for (int c = 0; c < 10; ++c) { e[c] = expf(lg[c] - mx); ssum += e[c]; }
    float inv = 1.f / ssum;
    #pragma unroll
    for (int c = 0; c < 10; ++c) out[b * 10 + c] = e[c] * inv;
  }
}

extern "C" void kernel_launch(void* const* d_in, const int* in_sizes, int n_in,
                              void* d_out, int out_size, void* d_ws, size_t ws_size,
                              hipStream_t stream)
{
  const float* In   = (const float*)d_in[0];
  const float* w1   = (const float*)d_in[1];
  const float* b1   = (const float*)d_in[2];
  const float* w2   = (const float*)d_in[3];
  const float* b2   = (const float*)d_in[4];
  const float* Rw   = (const float*)d_in[5];
  const float* Rb   = (const float*)d_in[6];
  const float* Qw   = (const float*)d_in[7];
  const float* Qb   = (const float*)d_in[8];
  const float* Ow   = (const float*)d_in[9];
  const float* Ob   = (const float*)d_in[10];
  const float* OutW = (const float*)d_in[11];
  const float* OutB = (const float*)d_in[12];
  float* out = (float*)d_out;

  float* ws  = (float*)d_ws;
  float* E   = ws;                   // [8192][750]            rows t*B+b
  float* EQp = E + 6144000;          // [4][8192][100] (EQ partials)
  float* Hf  = EQp + 4 * MROW;       // [8192][400]
  float* Op  = EQp;                  // O partials alias EQp (dead after scan)
  float* Pl  = E;                    // logits partials [64][128][10] alias E
  // total ~50.8 MB of d_ws (same as validated round-4 layout)

  hipLaunchKernelGGL(conv_embed_k, dim3(B_ * T_), dim3(256), 0, stream,
                     In, w1, b1, w2, b2, E);
  hipLaunchKernelGGL(gemm_part_k, dim3(64, 4), dim3(256), 0, stream,
                     E, Qw, EQp, 750, 4);
  hipLaunchKernelGGL(scan_k, dim3(B_), dim3(512), 0, stream,
                     EQp, Qb, Qw, Rw, Rb, Hf);
  hipLaunchKernelGGL(gemm_part_k, dim3(64, 4), dim3(256), 0, stream,
                     Hf, Ow, Op, 400, 2);
  hipLaunchKernelGGL(out_gemm_k, dim3(64), dim3(256), 0, stream,
                     Op, Ob, OutW, Pl);
  hipLaunchKernelGGL(softmax_k, dim3(B_), dim3(64), 0, stream,
                     Pl, OutB, out);
}

// Round 8
// 563.303 us; speedup vs baseline: 1.3797x; 1.1606x over previous
//
#include <hip/hip_runtime.h>
#include <math.h>

#define B_ 128
#define T_ 64
#define PH_ 52     // staged input rows: input row y -> y+1 (0..50; 0,51 halo)
#define PW2 64     // staged row stride: input col x -> x+1 (0..60; 0,61-63 halo)
#define EMB 750
#define MROW 819200  // 8192*100, one partial slab

// exact identity tanh(x) = 1 - 2/(e^{2x}+1); handles +-inf gracefully.
__device__ __forceinline__ float fast_tanh(float x) {
  float e = __expf(2.f * x);
  return 1.f - 2.f / (e + 1.f);
}

// exact 2-op LeakyReLU: for x<0, 0.01x > x; for x>=0, x >= 0.01x.
__device__ __forceinline__ float leaky(float x) {
  return fmaxf(x, 0.01f * x);
}

// ---------------- Kernel 1: run-based register-blocked conv (1 img/WG) ----
// Thread = (conv1 row r, 12-pixel x-run). 3x14 window loaded ONCE (float2).
// Channel groups of 4: weights hoisted per cg (s_loads amortized over 12 px).
// Waves parity-split (waves 0,1: even r; 2,3: odd r) -> wave-uniform fold
// branch; fold targets compile-time per pixel parity. conv2 partials in 14
// regs; single scatter of 7-14 LDS atomicAdds per thread at the end.
__global__ __launch_bounds__(256) void conv_embed_k(
    const float* __restrict__ In, const float* __restrict__ w1,
    const float* __restrict__ b1, const float* __restrict__ w2,
    const float* __restrict__ b2, float* __restrict__ E)
{
  __shared__ __align__(16) float sIn[PH_ * PW2];   // 3328 f = 13.3 KB
  __shared__ __align__(16) float sAcc[768];        // conv2 acc [i*30+j], 750 used

  const int tid = threadIdx.x;
  const int g = blockIdx.x;               // g = b*T + t
  const int b = g >> 6;
  const int t = g & 63;
  const float* src = In + (size_t)g * 3000;

  float4 z4 = make_float4(0.f, 0.f, 0.f, 0.f);
  float4* sIn4 = (float4*)sIn;            // 832 quads
  for (int i = tid; i < 832; i += 256) sIn4[i] = z4;
  float4* sAcc4 = (float4*)sAcc;          // 192 quads
  for (int i = tid; i < 192; i += 256) sAcc4[i] = z4;
  __syncthreads();
  for (int i = tid; i < 3000; i += 256) {
    int y = i / 60, x = i - y * 60;
    sIn[(y + 1) * PW2 + (x + 1)] = src[i];
  }
  __syncthreads();

  // mapping: waves 0,1 -> even rows; waves 2,3 -> odd rows (wave-uniform rp)
  const int rp = tid >> 7;              // row parity
  const int sub = tid & 127;
  const bool act = (sub < 125);
  const int rI = sub / 5;               // 0..24
  const int run = sub - rI * 5;         // 0..4
  const int r = 2 * rI + rp;            // conv1 row 0..49
  const int x0 = 12 * run;              // first conv1 col of the run
  const int cb = 6 * run;               // conv2 col base

  float acc[2][7];
  #pragma unroll
  for (int q = 0; q < 7; ++q) { acc[0][q] = 0.f; acc[1][q] = 0.f; }

  if (act) {
    // 3x14 window: win[ky][w] = input(r-1+ky, x0-1+w) = sIn[(r+ky)*64 + x0+w]
    float win[3][14];
    const float* wb = &sIn[r * PW2 + x0];     // even base -> float2 aligned
    #pragma unroll
    for (int wr = 0; wr < 3; ++wr) {
      const float2* rp2 = (const float2*)(wb + wr * PW2);
      #pragma unroll
      for (int q = 0; q < 7; ++q) {
        float2 v = rp2[q];
        win[wr][2 * q] = v.x; win[wr][2 * q + 1] = v.y;
      }
    }

    #pragma unroll 1    // keep one channel-group's weights live at a time
    for (int cg = 0; cg < 4; ++cg) {
      #pragma unroll
      for (int cc = 0; cc < 4; ++cc) {
        const int ch = cg * 4 + cc;
        float wv[9], w2v[9];
        #pragma unroll
        for (int q = 0; q < 9; ++q) { wv[q] = w1[ch * 9 + q]; w2v[q] = w2[ch * 9 + q]; }
        const float bias = b1[ch];

        #pragma unroll
        for (int u = 0; u < 12; ++u) {
          // conv1 at (r, x0+u): input cols x0+u-1 .. +1 -> win cols u..u+2
          float a = bias;
          #pragma unroll
          for (int ky = 0; ky < 3; ++ky) {
            a += wv[ky * 3 + 0] * win[ky][u + 0]
               + wv[ky * 3 + 1] * win[ky][u + 1]
               + wv[ky * 3 + 2] * win[ky][u + 2];
          }
          a = leaky(a);
          // fold into conv2 cells; weight w2[3*dy+dx], dy=r-2i+1, dx=x-2j+1
          if (rp == 0) {                 // wave-uniform: i=r/2, dy=1
            if ((u & 1) == 0) {          // x even: dx=1, j=x/2 -> jl=u/2
              acc[0][u / 2] += a * w2v[4];
            } else {                     // x odd: dx=2 @ jl=(u-1)/2; dx=0 @ (u+1)/2
              acc[0][(u - 1) / 2] += a * w2v[5];
              acc[0][(u + 1) / 2] += a * w2v[3];
            }
          } else {                       // i0=(r-1)/2 dy=2 (acc[0]); i1=i0+1 dy=0 (acc[1])
            if ((u & 1) == 0) {
              acc[0][u / 2] += a * w2v[7];
              acc[1][u / 2] += a * w2v[1];
            } else {
              acc[0][(u - 1) / 2] += a * w2v[8];
              acc[0][(u + 1) / 2] += a * w2v[6];
              acc[1][(u - 1) / 2] += a * w2v[2];
              acc[1][(u + 1) / 2] += a * w2v[0];
            }
          }
        }
      }
    }

    // scatter: acc[0] -> conv2 row rI; acc[1] (rp==1) -> row rI+1
    const int rowbase = rI * 30 + cb;
    #pragma unroll
    for (int jl = 0; jl < 7; ++jl) {
      if (cb + jl < 30) atomicAdd(&sAcc[rowbase + jl], acc[0][jl]);
    }
    if (rp == 1 && rI < 24) {
      #pragma unroll
      for (int jl = 0; jl < 7; ++jl) {
        if (cb + jl < 30) atomicAdd(&sAcc[rowbase + 30 + jl], acc[1][jl]);
      }
    }
  }
  __syncthreads();

  const float b2v = b2[0];
  float* erow = E + (size_t)(t * B_ + b) * EMB;
  for (int p = tid; p < 750; p += 256) erow[p] = leaky(sAcc[p] + b2v);
}

// ------- Kernel 2/4: partial GEMM  Part[s] = A[M,Ka] @ W[Ka,100] (K-split) --
__global__ __launch_bounds__(256) void gemm_part_k(
    const float* __restrict__ A, const float* __restrict__ W,
    float* __restrict__ Part, int Ka, int tps)
{
  __shared__ __align__(16) float AsT[50 * 132];   // [kk][row0..127 +4 pad]
  __shared__ __align__(16) float Ws[50 * 104];    // [kk][col0..99 +4 pad]

  const int tid = threadIdx.x;
  const int m0 = blockIdx.x * 128;
  const int s  = blockIdx.y;
  const int ktotal = Ka / 50;
  const int kt0 = s * tps;
  const int nt  = min(tps, ktotal - kt0);
  float* part = Part + (size_t)s * MROW;

  const int rq = tid & 15;
  const int cq = tid >> 4;
  const bool active = (cq < 13);
  const int lr0 = rq * 8;
  const int c0 = cq * 8;

  float acc[8][8];
  #pragma unroll
  for (int r = 0; r < 8; ++r)
    #pragma unroll
    for (int c = 0; c < 8; ++c) acc[r][c] = 0.f;

  for (int kt = 0; kt < nt; ++kt) {
    const int k0 = (kt0 + kt) * 50;
    // A: 128 rows x 50 k, float2 (Ka and k0 even -> 8B aligned)
    for (int i = tid; i < 3200; i += 256) {
      int rr = i / 25, kk2 = (i - rr * 25) * 2;
      float2 v = *(const float2*)&A[(size_t)(m0 + rr) * Ka + k0 + kk2];
      AsT[kk2 * 132 + rr] = v.x;
      AsT[(kk2 + 1) * 132 + rr] = v.y;
    }
    // W: 50 k x 100 cols, float4
    for (int i = tid; i < 1250; i += 256) {
      int kk = i / 25, c4 = (i - kk * 25) * 4;
      float4 v = *(const float4*)&W[(size_t)(k0 + kk) * 100 + c4];
      *(float4*)&Ws[kk * 104 + c4] = v;
    }
    __syncthreads();
    if (active) {
      for (int kk = 0; kk < 50; ++kk) {
        float4 a0 = *(const float4*)&AsT[kk * 132 + lr0];
        float4 a1 = *(const float4*)&AsT[kk * 132 + lr0 + 4];
        float4 w0 = *(const float4*)&Ws[kk * 104 + c0];
        float4 w1v = *(const float4*)&Ws[kk * 104 + c0 + 4];
        float av[8] = {a0.x, a0.y, a0.z, a0.w, a1.x, a1.y, a1.z, a1.w};
        float wv[8] = {w0.x, w0.y, w0.z, w0.w, w1v.x, w1v.y, w1v.z, w1v.w};
        #pragma unroll
        for (int r = 0; r < 8; ++r)
          #pragma unroll
          for (int c = 0; c < 8; ++c) acc[r][c] += av[r] * wv[c];
      }
    }
    __syncthreads();
  }

  if (active) {
    #pragma unroll
    for (int r = 0; r < 8; ++r) {
      float* pp = part + (size_t)(m0 + lr0 + r) * 100 + c0;
      *(float4*)pp = make_float4(acc[r][0], acc[r][1], acc[r][2], acc[r][3]);
      if (cq < 12)
        *(float4*)(pp + 4) = make_float4(acc[r][4], acc[r][5], acc[r][6], acc[r][7]);
    }
  }
}

// ---------------- Kernel 3: sequential scan + fused H-scan (validated) ----
__global__ __launch_bounds__(512) void scan_k(
    const float* __restrict__ EQp, const float* __restrict__ Qb,
    const float* __restrict__ Qw, const float* __restrict__ Rw,
    const float* __restrict__ Rb, float* __restrict__ Hf)
{
  __shared__ __align__(16) float sEQ[T_ * 100];   // 25.6 KB
  __shared__ __align__(16) float sQ[100];
  __shared__ float sR[100];
  __shared__ float sGred[400];
  __shared__ float sP2[400];

  const int tid = threadIdx.x;
  const int b = blockIdx.x;
  const bool owner = (tid < 400);
  const int a = tid / 100;
  const int j = tid - a * 100;
  const float al = (a == 0) ? 0.f : (a == 1) ? 0.25f : (a == 2) ? 0.5f : 0.95f;

  {
    const float4* Qb4 = (const float4*)Qb;
    float4* sEQ4 = (float4*)sEQ;
    for (int i4 = tid; i4 < 1600; i4 += 512) {
      int tt = i4 / 25, j4 = i4 - tt * 25;
      size_t idx4 = (size_t)(tt * B_ + b) * 25 + j4;
      const float4* p0 = (const float4*)EQp;
      float4 v0 = p0[idx4];
      float4 v1 = p0[MROW / 4 + idx4];
      float4 v2 = p0[2 * (MROW / 4) + idx4];
      float4 v3 = p0[3 * (MROW / 4) + idx4];
      float4 qb = Qb4[j4];
      sEQ4[i4] = make_float4(v0.x + v1.x + v2.x + v3.x + qb.x,
                             v0.y + v1.y + v2.y + v3.y + qb.y,
                             v0.z + v1.z + v2.z + v3.z + qb.z,
                             v0.w + v1.w + v2.w + v3.w + qb.w);
    }
  }

  float rw[100];
  float qw[25];
  if (owner) {
    const float* rp = Rw + (size_t)a * 10000 + j;
    #pragma unroll
    for (int k = 0; k < 100; ++k) rw[k] = rp[(size_t)k * 100];
    const float* qp = Qw + (size_t)(750 + a * 25) * 100 + j;
    #pragma unroll
    for (int kk = 0; kk < 25; ++kk) qw[kk] = qp[(size_t)kk * 100];
    sGred[tid] = 0.f;
  }
  const float rb = (tid < 100) ? Rb[tid] : 0.f;
  float g = 0.f;
  float h1 = 0.f, h2 = 0.f, h3 = 0.f;
  __syncthreads();

  for (int t = 0; t < T_; ++t) {
    if (tid < 100) {
      float s = sGred[tid] + sGred[100 + tid] + sGred[200 + tid] + sGred[300 + tid] + rb;
      sR[tid] = fast_tanh(s);
    }
    __syncthreads();
    if (owner) {
      float p = 0.f;
      #pragma unroll
      for (int kk = 0; kk < 25; ++kk) p += sR[a * 25 + kk] * qw[kk];
      sP2[tid] = p;
    }
    __syncthreads();
    if (tid < 100) {
      float q = fast_tanh(sEQ[t * 100 + tid] +
                          sP2[tid] + sP2[100 + tid] + sP2[200 + tid] + sP2[300 + tid]);
      sQ[tid] = q;
      h1 = 0.25f * h1 + 0.75f * q;
      h2 = 0.50f * h2 + 0.50f * q;
      h3 = 0.95f * h3 + 0.05f * q;
      float* hp = Hf + (size_t)(t * B_ + b) * 400 + tid;
      hp[0] = q; hp[100] = h1; hp[200] = h2; hp[300] = h3;
    }
    __syncthreads();
    if (owner) {
      float d = 0.f;
      const float4* q4 = (const float4*)sQ;
      #pragma unroll
      for (int k4 = 0; k4 < 25; ++k4) {
        float4 qv = q4[k4];
        d += qv.x * rw[k4 * 4] + qv.y * rw[k4 * 4 + 1]
           + qv.z * rw[k4 * 4 + 2] + qv.w * rw[k4 * 4 + 3];
      }
      g = al * g + (1.f - al) * d;
      sGred[tid] = g;
    }
    __syncthreads();
  }
}

// ------- Kernel 5: split-K logits partials, LDS-staged (coalesced) --------
// Block kb: stages sum of 4 Opart slabs (+Ob, tanh) for rows kb*128..+127
// into LDS with fully contiguous global reads, then the 100-k GEMM from LDS.
__global__ __launch_bounds__(256) void out_gemm_k(
    const float* __restrict__ Opart, const float* __restrict__ Ob,
    const float* __restrict__ OutW, float* __restrict__ Pl)
{
  __shared__ float sW[1104];           // [0..999] OutW rows kb*100..+99; [1000..1099] Ob
  __shared__ float sO[12800];          // tanh'd O rows for this kb (51.2 KB)
  const int tid = threadIdx.x;
  const int kb = blockIdx.x;           // 0..63 == t
  for (int i = tid; i < 1000; i += 256) sW[i] = OutW[kb * 1000 + i];
  if (tid < 100) sW[1000 + tid] = Ob[tid];
  __syncthreads();

  for (int i = tid; i < 12800; i += 256) {
    const size_t idx = (size_t)kb * 12800 + i;    // contiguous: (kb*128+row)*100+j
    float p = Opart[idx] + Opart[MROW + idx] + Opart[2 * MROW + idx] + Opart[3 * MROW + idx];
    sO[i] = fast_tanh(p + sW[1000 + (i - (i / 100) * 100)]);
  }
  __syncthreads();

  const int bb = tid >> 1;             // sample 0..127
  const int half = tid & 1;            // k-half
  float acc[10];
  #pragma unroll
  for (int c = 0; c < 10; ++c) acc[c] = 0.f;

  for (int kk = 0; kk < 50; ++kk) {
    const int off = half * 50 + kk;
    float o = sO[bb * 100 + off];
    const float* w = &sW[off * 10];
    #pragma unroll
    for (int c = 0; c < 10; ++c) acc[c] += o * w[c];
  }
  #pragma unroll
  for (int c = 0; c < 10; ++c) acc[c] += __shfl_xor(acc[c], 1, 2);
  if (half == 0) {
    float* pp = &Pl[(size_t)kb * 1280 + bb * 10];
    #pragma unroll
    for (int c = 0; c < 10; ++c) pp[c] = acc[c];
  }
}

// ------- Kernel 6: reduce 64 partials + bias + softmax. 128 blocks x 64 thr.
__global__ __launch_bounds__(64) void softmax_k(
    const float* __restrict__ Pl, const float* __restrict__ OutB,
    float* __restrict__ out)
{
  const int b = blockIdx.x;
  const int lane = threadIdx.x;        // = kb
  float acc[10];
  const float* pp = &Pl[(size_t)lane * 1280 + b * 10];
  #pragma unroll
  for (int c = 0; c < 10; ++c) acc[c] = pp[c];
  #pragma unroll
  for (int sdl = 32; sdl >= 1; sdl >>= 1) {
    #pragma unroll
    for (int c = 0; c < 10; ++c) acc[c] += __shfl_down(acc[c], sdl, 64);
  }
  if (lane == 0) {
    float lg[10];
    #pragma unroll
    for (int c = 0; c < 10; ++c) lg[c] = acc[c] + OutB[c];
    float mx = lg[0];
    #pragma unroll
    for (int c = 1; c < 10; ++c) mx = fmaxf(mx, lg[c]);
    float e[10], ssum = 0.f;
    #pragma unroll
    for (int c = 0; c < 10; ++c) { e[c] = expf(lg[c] - mx); ssum += e[c]; }
    float inv = 1.f / ssum;
    #pragma unroll
    for (int c = 0; c < 10; ++c) out[b * 10 + c] = e[c] * inv;
  }
}

extern "C" void kernel_launch(void* const* d_in, const int* in_sizes, int n_in,
                              void* d_out, int out_size, void* d_ws, size_t ws_size,
                              hipStream_t stream)
{
  const float* In   = (const float*)d_in[0];
  const float* w1   = (const float*)d_in[1];
  const float* b1   = (const float*)d_in[2];
  const float* w2   = (const float*)d_in[3];
  const float* b2   = (const float*)d_in[4];
  const float* Rw   = (const float*)d_in[5];
  const float* Rb   = (const float*)d_in[6];
  const float* Qw   = (const float*)d_in[7];
  const float* Qb   = (const float*)d_in[8];
  const float* Ow   = (const float*)d_in[9];
  const float* Ob   = (const float*)d_in[10];
  const float* OutW = (const float*)d_in[11];
  const float* OutB = (const float*)d_in[12];
  float* out = (float*)d_out;

  float* ws  = (float*)d_ws;
  float* E   = ws;                   // [8192][750]            rows t*B+b
  float* EQp = E + 6144000;          // [4][8192][100] (EQ partials)
  float* Hf  = EQp + 4 * MROW;       // [8192][400]
  float* Op  = EQp;                  // O partials alias EQp (dead after scan)
  float* Pl  = E;                    // logits partials [64][128][10] alias E
  // total ~50.8 MB of d_ws (same validated layout)

  hipLaunchKernelGGL(conv_embed_k, dim3(B_ * T_), dim3(256), 0, stream,
                     In, w1, b1, w2, b2, E);
  hipLaunchKernelGGL(gemm_part_k, dim3(64, 4), dim3(256), 0, stream,
                     E, Qw, EQp, 750, 4);
  hipLaunchKernelGGL(scan_k, dim3(B_), dim3(512), 0, stream,
                     EQp, Qb, Qw, Rw, Rb, Hf);
  hipLaunchKernelGGL(gemm_part_k, dim3(64, 4), dim3(256), 0, stream,
                     Hf, Ow, Op, 400, 2);
  hipLaunchKernelGGL(out_gemm_k, dim3(64), dim3(256), 0, stream,
                     Op, Ob, OutW, Pl);
  hipLaunchKernelGGL(softmax_k, dim3(B_), dim3(64), 0, stream,
                     Pl, OutB, out);
}

// Round 9
// 550.079 us; speedup vs baseline: 1.4129x; 1.0240x over previous
//
#include <hip/hip_runtime.h>
#include <math.h>

#define B_ 128
#define T_ 64
#define PH_ 52     // staged input rows: input row y -> y+1 (0..50; 0,51 halo)
#define PW2 64     // staged row stride: input col x -> x+1 (0..60; 0,61-63 halo)
#define EMB 750
#define MROW 819200  // 8192*100, one partial slab

// exact identity tanh(x) = 1 - 2/(e^{2x}+1); handles +-inf gracefully.
__device__ __forceinline__ float fast_tanh(float x) {
  float e = __expf(2.f * x);
  return 1.f - 2.f / (e + 1.f);
}

// exact 2-op LeakyReLU: for x<0, 0.01x > x; for x>=0, x >= 0.01x.
__device__ __forceinline__ float leaky(float x) {
  return fmaxf(x, 0.01f * x);
}

// ---------------- Kernel 1: run-based register-blocked conv (1 img/WG) ----
// Thread = (conv1 row r, 12-pixel x-run). 3x14 window in regs, loaded ONCE.
// __launch_bounds__(256,4) -> 128-VGPR cap so window+weights+acc stay
// RESIDENT (round-8's 64-VGPR cap forced rematerialization = 3x VALU).
// Weights blocked per-channel (#pragma unroll 1): live set ~90 VGPR.
__global__ __launch_bounds__(256, 4) void conv_embed_k(
    const float* __restrict__ In, const float* __restrict__ w1,
    const float* __restrict__ b1, const float* __restrict__ w2,
    const float* __restrict__ b2, float* __restrict__ E)
{
  __shared__ __align__(16) float sIn[PH_ * PW2];   // 3328 f = 13.3 KB
  __shared__ __align__(16) float sAcc[768];        // conv2 acc [i*30+j], 750 used

  const int tid = threadIdx.x;
  const int g = blockIdx.x;               // g = b*T + t
  const int b = g >> 6;
  const int t = g & 63;
  const float* src = In + (size_t)g * 3000;

  float4 z4 = make_float4(0.f, 0.f, 0.f, 0.f);
  float4* sIn4 = (float4*)sIn;            // 832 quads
  for (int i = tid; i < 832; i += 256) sIn4[i] = z4;
  float4* sAcc4 = (float4*)sAcc;          // 192 quads
  for (int i = tid; i < 192; i += 256) sAcc4[i] = z4;
  __syncthreads();
  for (int i = tid; i < 3000; i += 256) {
    int y = i / 60, x = i - y * 60;
    sIn[(y + 1) * PW2 + (x + 1)] = src[i];
  }
  __syncthreads();

  // waves 0,1 -> even conv1 rows; waves 2,3 -> odd rows (wave-uniform rp)
  const int rp = tid >> 7;              // row parity
  const int sub = tid & 127;
  const bool act = (sub < 125);
  const int rI = sub / 5;               // 0..24
  const int run = sub - rI * 5;         // 0..4
  const int r = 2 * rI + rp;            // conv1 row 0..49
  const int x0 = 12 * run;              // first conv1 col of the run
  const int cb = 6 * run;               // conv2 col base

  float acc[2][7];
  #pragma unroll
  for (int q = 0; q < 7; ++q) { acc[0][q] = 0.f; acc[1][q] = 0.f; }

  if (act) {
    // 3x14 window: win[ky][w] = input(r-1+ky, x0-1+w) = sIn[(r+ky)*64 + x0+w]
    float win[3][14];
    const float* wb = &sIn[r * PW2 + x0];     // even base -> float2 aligned
    #pragma unroll
    for (int wr = 0; wr < 3; ++wr) {
      const float2* rp2 = (const float2*)(wb + wr * PW2);
      #pragma unroll
      for (int q = 0; q < 7; ++q) {
        float2 v = rp2[q];
        win[wr][2 * q] = v.x; win[wr][2 * q + 1] = v.y;
      }
    }

    #pragma unroll 1    // one channel's weights live at a time (~19 regs)
    for (int ch = 0; ch < 16; ++ch) {
      float wv[9], w2v[9];
      #pragma unroll
      for (int q = 0; q < 9; ++q) { wv[q] = w1[ch * 9 + q]; w2v[q] = w2[ch * 9 + q]; }
      const float bias = b1[ch];

      #pragma unroll
      for (int u = 0; u < 12; ++u) {
        // conv1 at (r, x0+u): input cols x0+u-1..+1 -> win cols u..u+2
        float a = bias;
        #pragma unroll
        for (int ky = 0; ky < 3; ++ky) {
          a += wv[ky * 3 + 0] * win[ky][u + 0]
             + wv[ky * 3 + 1] * win[ky][u + 1]
             + wv[ky * 3 + 2] * win[ky][u + 2];
        }
        a = leaky(a);
        // fold into conv2 cells; weight w2[3*dy+dx], dy=r-2i+1, dx=x-2j+1
        if (rp == 0) {                 // wave-uniform: i=r/2, dy=1
          if ((u & 1) == 0) {          // x even: dx=1 @ jl=u/2
            acc[0][u / 2] += a * w2v[4];
          } else {                     // x odd: dx=2 @ (u-1)/2; dx=0 @ (u+1)/2
            acc[0][(u - 1) / 2] += a * w2v[5];
            acc[0][(u + 1) / 2] += a * w2v[3];
          }
        } else {                       // i0=(r-1)/2 dy=2 (acc[0]); i1=i0+1 dy=0 (acc[1])
          if ((u & 1) == 0) {
            acc[0][u / 2] += a * w2v[7];
            acc[1][u / 2] += a * w2v[1];
          } else {
            acc[0][(u - 1) / 2] += a * w2v[8];
            acc[0][(u + 1) / 2] += a * w2v[6];
            acc[1][(u - 1) / 2] += a * w2v[2];
            acc[1][(u + 1) / 2] += a * w2v[0];
          }
        }
      }
    }

    // scatter: acc[0] -> conv2 row rI; acc[1] (rp==1) -> row rI+1
    const int rowbase = rI * 30 + cb;
    #pragma unroll
    for (int jl = 0; jl < 7; ++jl) {
      if (cb + jl < 30) atomicAdd(&sAcc[rowbase + jl], acc[0][jl]);
    }
    if (rp == 1 && rI < 24) {
      #pragma unroll
      for (int jl = 0; jl < 7; ++jl) {
        if (cb + jl < 30) atomicAdd(&sAcc[rowbase + 30 + jl], acc[1][jl]);
      }
    }
  }
  __syncthreads();

  const float b2v = b2[0];
  float* erow = E + (size_t)(t * B_ + b) * EMB;
  for (int p = tid; p < 750; p += 256) erow[p] = leaky(sAcc[p] + b2v);
}

// ------- Kernel 2/4: partial GEMM  Part[s] = A[M,Ka] @ W[Ka,100] (K-split) --
// BM=64 M-tiles -> grid (128, NS) = 512 blocks = 2/CU (round-8's 256 = 1/CU
// had zero TLP). 256 thr: 16 rgrp x 13 active cgrp, 4x8 register tile.
__global__ __launch_bounds__(256) void gemm_part_k(
    const float* __restrict__ A, const float* __restrict__ W,
    float* __restrict__ Part, int Ka, int tps)
{
  __shared__ __align__(16) float AsT[50 * 68];    // [kk][row0..63 +4 pad]
  __shared__ __align__(16) float Ws[50 * 104];    // [kk][col0..99 +4 pad]

  const int tid = threadIdx.x;
  const int m0 = blockIdx.x * 64;
  const int s  = blockIdx.y;
  const int ktotal = Ka / 50;
  const int kt0 = s * tps;
  const int nt  = min(tps, ktotal - kt0);
  float* part = Part + (size_t)s * MROW;

  const int rq = tid & 15;          // 16 row groups x 4 rows
  const int cq = tid >> 4;          // 16 col groups; active < 13
  const bool active = (cq < 13);
  const int lr0 = rq * 4;
  const int c0 = cq * 8;

  float acc[4][8];
  #pragma unroll
  for (int r = 0; r < 4; ++r)
    #pragma unroll
    for (int c = 0; c < 8; ++c) acc[r][c] = 0.f;

  for (int kt = 0; kt < nt; ++kt) {
    const int k0 = (kt0 + kt) * 50;
    // A: 64 rows x 50 k, float2 (Ka, k0 even -> 8B aligned)
    for (int i = tid; i < 1600; i += 256) {
      int rr = i / 25, kk2 = (i - rr * 25) * 2;
      float2 v = *(const float2*)&A[(size_t)(m0 + rr) * Ka + k0 + kk2];
      AsT[kk2 * 68 + rr] = v.x;
      AsT[(kk2 + 1) * 68 + rr] = v.y;
    }
    // W: 50 k x 100 cols, float4
    for (int i = tid; i < 1250; i += 256) {
      int kk = i / 25, c4 = (i - kk * 25) * 4;
      float4 v = *(const float4*)&W[(size_t)(k0 + kk) * 100 + c4];
      *(float4*)&Ws[kk * 104 + c4] = v;
    }
    __syncthreads();
    if (active) {
      for (int kk = 0; kk < 50; ++kk) {
        float4 a0 = *(const float4*)&AsT[kk * 68 + lr0];
        float4 w0 = *(const float4*)&Ws[kk * 104 + c0];
        float4 w1v = *(const float4*)&Ws[kk * 104 + c0 + 4];
        float av[4] = {a0.x, a0.y, a0.z, a0.w};
        float wv[8] = {w0.x, w0.y, w0.z, w0.w, w1v.x, w1v.y, w1v.z, w1v.w};
        #pragma unroll
        for (int r = 0; r < 4; ++r)
          #pragma unroll
          for (int c = 0; c < 8; ++c) acc[r][c] += av[r] * wv[c];
      }
    }
    __syncthreads();
  }

  if (active) {
    #pragma unroll
    for (int r = 0; r < 4; ++r) {
      float* pp = part + (size_t)(m0 + lr0 + r) * 100 + c0;
      *(float4*)pp = make_float4(acc[r][0], acc[r][1], acc[r][2], acc[r][3]);
      if (cq < 12)   // col group 12 covers exactly cols 96..99
        *(float4*)(pp + 4) = make_float4(acc[r][4], acc[r][5], acc[r][6], acc[r][7]);
    }
  }
}

// ---------------- Kernel 3: sequential scan + fused H-scan (validated) ----
__global__ __launch_bounds__(512) void scan_k(
    const float* __restrict__ EQp, const float* __restrict__ Qb,
    const float* __restrict__ Qw, const float* __restrict__ Rw,
    const float* __restrict__ Rb, float* __restrict__ Hf)
{
  __shared__ __align__(16) float sEQ[T_ * 100];   // 25.6 KB
  __shared__ __align__(16) float sQ[100];
  __shared__ float sR[100];
  __shared__ float sGred[400];
  __shared__ float sP2[400];

  const int tid = threadIdx.x;
  const int b = blockIdx.x;
  const bool owner = (tid < 400);
  const int a = tid / 100;
  const int j = tid - a * 100;
  const float al = (a == 0) ? 0.f : (a == 1) ? 0.25f : (a == 2) ? 0.5f : 0.95f;

  {
    const float4* Qb4 = (const float4*)Qb;
    float4* sEQ4 = (float4*)sEQ;
    for (int i4 = tid; i4 < 1600; i4 += 512) {
      int tt = i4 / 25, j4 = i4 - tt * 25;
      size_t idx4 = (size_t)(tt * B_ + b) * 25 + j4;
      const float4* p0 = (const float4*)EQp;
      float4 v0 = p0[idx4];
      float4 v1 = p0[MROW / 4 + idx4];
      float4 v2 = p0[2 * (MROW / 4) + idx4];
      float4 v3 = p0[3 * (MROW / 4) + idx4];
      float4 qb = Qb4[j4];
      sEQ4[i4] = make_float4(v0.x + v1.x + v2.x + v3.x + qb.x,
                             v0.y + v1.y + v2.y + v3.y + qb.y,
                             v0.z + v1.z + v2.z + v3.z + qb.z,
                             v0.w + v1.w + v2.w + v3.w + qb.w);
    }
  }

  float rw[100];
  float qw[25];
  if (owner) {
    const float* rp = Rw + (size_t)a * 10000 + j;
    #pragma unroll
    for (int k = 0; k < 100; ++k) rw[k] = rp[(size_t)k * 100];
    const float* qp = Qw + (size_t)(750 + a * 25) * 100 + j;
    #pragma unroll
    for (int kk = 0; kk < 25; ++kk) qw[kk] = qp[(size_t)kk * 100];
    sGred[tid] = 0.f;
  }
  const float rb = (tid < 100) ? Rb[tid] : 0.f;
  float g = 0.f;
  float h1 = 0.f, h2 = 0.f, h3 = 0.f;
  __syncthreads();

  for (int t = 0; t < T_; ++t) {
    if (tid < 100) {
      float s = sGred[tid] + sGred[100 + tid] + sGred[200 + tid] + sGred[300 + tid] + rb;
      sR[tid] = fast_tanh(s);
    }
    __syncthreads();
    if (owner) {
      float p = 0.f;
      #pragma unroll
      for (int kk = 0; kk < 25; ++kk) p += sR[a * 25 + kk] * qw[kk];
      sP2[tid] = p;
    }
    __syncthreads();
    if (tid < 100) {
      float q = fast_tanh(sEQ[t * 100 + tid] +
                          sP2[tid] + sP2[100 + tid] + sP2[200 + tid] + sP2[300 + tid]);
      sQ[tid] = q;
      h1 = 0.25f * h1 + 0.75f * q;
      h2 = 0.50f * h2 + 0.50f * q;
      h3 = 0.95f * h3 + 0.05f * q;
      float* hp = Hf + (size_t)(t * B_ + b) * 400 + tid;
      hp[0] = q; hp[100] = h1; hp[200] = h2; hp[300] = h3;
    }
    __syncthreads();
    if (owner) {
      float d = 0.f;
      const float4* q4 = (const float4*)sQ;
      #pragma unroll
      for (int k4 = 0; k4 < 25; ++k4) {
        float4 qv = q4[k4];
        d += qv.x * rw[k4 * 4] + qv.y * rw[k4 * 4 + 1]
           + qv.z * rw[k4 * 4 + 2] + qv.w * rw[k4 * 4 + 3];
      }
      g = al * g + (1.f - al) * d;
      sGred[tid] = g;
    }
    __syncthreads();
  }
}

// ------- Kernel 5: split-K logits partials, LDS-staged (coalesced) --------
__global__ __launch_bounds__(256) void out_gemm_k(
    const float* __restrict__ Opart, const float* __restrict__ Ob,
    const float* __restrict__ OutW, float* __restrict__ Pl)
{
  __shared__ float sW[1104];           // [0..999] OutW rows kb*100..+99; [1000..1099] Ob
  __shared__ float sO[12800];          // tanh'd O rows for this kb (51.2 KB)
  const int tid = threadIdx.x;
  const int kb = blockIdx.x;           // 0..63 == t
  for (int i = tid; i < 1000; i += 256) sW[i] = OutW[kb * 1000 + i];
  if (tid < 100) sW[1000 + tid] = Ob[tid];
  __syncthreads();

  for (int i = tid; i < 12800; i += 256) {
    const size_t idx = (size_t)kb * 12800 + i;    // contiguous: (kb*128+row)*100+j
    float p = Opart[idx] + Opart[MROW + idx] + Opart[2 * MROW + idx] + Opart[3 * MROW + idx];
    sO[i] = fast_tanh(p + sW[1000 + (i - (i / 100) * 100)]);
  }
  __syncthreads();

  const int bb = tid >> 1;             // sample 0..127
  const int half = tid & 1;            // k-half
  float acc[10];
  #pragma unroll
  for (int c = 0; c < 10; ++c) acc[c] = 0.f;

  for (int kk = 0; kk < 50; ++kk) {
    const int off = half * 50 + kk;
    float o = sO[bb * 100 + off];
    const float* w = &sW[off * 10];
    #pragma unroll
    for (int c = 0; c < 10; ++c) acc[c] += o * w[c];
  }
  #pragma unroll
  for (int c = 0; c < 10; ++c) acc[c] += __shfl_xor(acc[c], 1, 2);
  if (half == 0) {
    float* pp = &Pl[(size_t)kb * 1280 + bb * 10];
    #pragma unroll
    for (int c = 0; c < 10; ++c) pp[c] = acc[c];
  }
}

// ------- Kernel 6: reduce 64 partials + bias + softmax. 128 blocks x 64 thr.
__global__ __launch_bounds__(64) void softmax_k(
    const float* __restrict__ Pl, const float* __restrict__ OutB,
    float* __restrict__ out)
{
  const int b = blockIdx.x;
  const int lane = threadIdx.x;        // = kb
  float acc[10];
  const float* pp = &Pl[(size_t)lane * 1280 + b * 10];
  #pragma unroll
  for (int c = 0; c < 10; ++c) acc[c] = pp[c];
  #pragma unroll
  for (int sdl = 32; sdl >= 1; sdl >>= 1) {
    #pragma unroll
    for (int c = 0; c < 10; ++c) acc[c] += __shfl_down(acc[c], sdl, 64);
  }
  if (lane == 0) {
    float lg[10];
    #pragma unroll
    for (int c = 0; c < 10; ++c) lg[c] = acc[c] + OutB[c];
    float mx = lg[0];
    #pragma unroll
    for (int c = 1; c < 10; ++c) mx = fmaxf(mx, lg[c]);
    float e[10], ssum = 0.f;
    #pragma unroll
    for (int c = 0; c < 10; ++c) { e[c] = expf(lg[c] - mx); ssum += e[c]; }
    float inv = 1.f / ssum;
    #pragma unroll
    for (int c = 0; c < 10; ++c) out[b * 10 + c] = e[c] * inv;
  }
}

extern "C" void kernel_launch(void* const* d_in, const int* in_sizes, int n_in,
                              void* d_out, int out_size, void* d_ws, size_t ws_size,
                              hipStream_t stream)
{
  const float* In   = (const float*)d_in[0];
  const float* w1   = (const float*)d_in[1];
  const float* b1   = (const float*)d_in[2];
  const float* w2   = (const float*)d_in[3];
  const float* b2   = (const float*)d_in[4];
  const float* Rw   = (const float*)d_in[5];
  const float* Rb   = (const float*)d_in[6];
  const float* Qw   = (const float*)d_in[7];
  const float* Qb   = (const float*)d_in[8];
  const float* Ow   = (const float*)d_in[9];
  const float* Ob   = (const float*)d_in[10];
  const float* OutW = (const float*)d_in[11];
  const float* OutB = (const float*)d_in[12];
  float* out = (float*)d_out;

  float* ws  = (float*)d_ws;
  float* E   = ws;                   // [8192][750]            rows t*B+b
  float* EQp = E + 6144000;          // [4][8192][100] (EQ partials)
  float* Hf  = EQp + 4 * MROW;       // [8192][400]
  float* Op  = EQp;                  // O partials alias EQp (dead after scan)
  float* Pl  = E;                    // logits partials [64][128][10] alias E
  // total ~50.8 MB of d_ws (same validated layout)

  hipLaunchKernelGGL(conv_embed_k, dim3(B_ * T_), dim3(256), 0, stream,
                     In, w1, b1, w2, b2, E);
  hipLaunchKernelGGL(gemm_part_k, dim3(128, 4), dim3(256), 0, stream,
                     E, Qw, EQp, 750, 4);
  hipLaunchKernelGGL(scan_k, dim3(B_), dim3(512), 0, stream,
                     EQp, Qb, Qw, Rw, Rb, Hf);
  hipLaunchKernelGGL(gemm_part_k, dim3(128, 4), dim3(256), 0, stream,
                     Hf, Ow, Op, 400, 2);
  hipLaunchKernelGGL(out_gemm_k, dim3(64), dim3(256), 0, stream,
                     Op, Ob, OutW, Pl);
  hipLaunchKernelGGL(softmax_k, dim3(B_), dim3(64), 0, stream,
                     Pl, OutB, out);
}